// Round 3
// baseline (872.786 us; speedup 1.0000x reference)
//
#include <hip/hip_runtime.h>
#include <math.h>

typedef unsigned short u16;
typedef unsigned int   u32;
typedef __attribute__((ext_vector_type(8))) short bf16x8;
typedef __attribute__((ext_vector_type(4))) float f32x4;
typedef __attribute__((ext_vector_type(4))) u32   u32x4;

#define IMG_W 96
#define IMG_H 96
#define HWSZ  9216
#define CCH   128
#define BATCH 8
#define NT    4

#define PADW  102
#define PADA  (102*102)
#define XBF_ELEMS ((size_t)BATCH*PADA*CCH)
#define XBF_BYTES (XBF_ELEMS*2)

#define XS_ELEMS (BATCH*CCH*HWSZ)
#define ES_OFF   (4*XS_ELEMS)

__device__ inline u16 f2bf(float f) {
    u32 u = __float_as_uint(f);
    u += 0x7fffu + ((u >> 16) & 1u);
    return (u16)(u >> 16);
}
__device__ inline float bf2f(u16 h) {
    return __uint_as_float(((u32)h) << 16);
}

#define GLD_LDS16(g, l) \
    __builtin_amdgcn_global_load_lds((const __attribute__((address_space(1))) void*)(g), \
                                     (__attribute__((address_space(3))) void*)(l), 16, 0, 0)

// ---------------------------------------------------------------------------
// GroupNorm stats
// ---------------------------------------------------------------------------
__global__ __launch_bounds__(256) void gn_stats_kernel(
    const float* __restrict__ c, float* __restrict__ stats)
{
    const int bg  = blockIdx.x;
    const int tid = threadIdx.x;
    const float4* p4 = (const float4*)(c + (size_t)bg * 18432);
    float s1 = 0.f, s2 = 0.f;
    for (int i = tid; i < 18432/4; i += 256) {
        float4 v = p4[i];
        s1 += v.x + v.y + v.z + v.w;
        s2 += v.x*v.x + v.y*v.y + v.z*v.z + v.w*v.w;
    }
    __shared__ float r1[256], r2[256];
    r1[tid] = s1; r2[tid] = s2;
    __syncthreads();
    for (int s = 128; s > 0; s >>= 1) {
        if (tid < s) { r1[tid] += r1[tid+s]; r2[tid] += r2[tid+s]; }
        __syncthreads();
    }
    if (tid == 0) {
        float mu  = r1[0] * (1.f/18432.f);
        float var = fmaxf(r2[0] * (1.f/18432.f) - mu*mu, 0.f);
        stats[bg*2]   = mu;
        stats[bg*2+1] = rsqrtf(var + 1e-5f);
    }
}

// ---------------------------------------------------------------------------
// Weight reorder: conv_w f32 [oc][ic][7][7] -> wbf bf16 [tap][oc][ic]
// ---------------------------------------------------------------------------
__global__ __launch_bounds__(256) void wprep_kernel(
    const float* __restrict__ cw, u16* __restrict__ wbf)
{
    int idx = blockIdx.x * 256 + threadIdx.x;
    if (idx >= 128*128*49) return;
    int tap = idx % 49;
    int rem = idx / 49;
    int ic  = rem % 128;
    int oc  = rem / 128;
    wbf[(size_t)tap*16384 + oc*128 + ic] = f2bf(cw[idx]);
}

// ---------------------------------------------------------------------------
// cgn prep: GN-affine(c) + conv bias, packed bf16 pairs, planar per group.
// cgn[(b*64+g)*9216 + pix] = u32(bf16(ch 2g), bf16(ch 2g+1))
// ---------------------------------------------------------------------------
__global__ __launch_bounds__(256) void cprep_kernel(
    const float* __restrict__ c, const float* __restrict__ stats,
    const float* __restrict__ gnw, const float* __restrict__ gnb,
    const float* __restrict__ cb, u32* __restrict__ cgn)
{
    const int bg  = blockIdx.y;            // b*64+g
    const int pix = blockIdx.x * 1024 + threadIdx.x * 4;
    const int b   = bg >> 6, g = bg & 63;
    const int ch0 = 2*g, ch1 = 2*g + 1;
    const float mu = stats[bg*2], rs = stats[bg*2+1];
    const float w0 = gnw[ch0]*rs, b0 = gnb[ch0] - mu*w0 + cb[ch0];
    const float w1 = gnw[ch1]*rs, b1 = gnb[ch1] - mu*w1 + cb[ch1];
    f32x4 c0 = *(const f32x4*)(c + ((size_t)(b*128+ch0))*HWSZ + pix);
    f32x4 c1 = *(const f32x4*)(c + ((size_t)(b*128+ch1))*HWSZ + pix);
    u32x4 v;
    #pragma unroll
    for (int j = 0; j < 4; ++j)
        v[j] = (u32)f2bf(fmaf(c0[j], w0, b0)) | ((u32)f2bf(fmaf(c1[j], w1, b1)) << 16);
    *(u32x4*)(cgn + (size_t)bg*HWSZ + pix) = v;
}

// ---------------------------------------------------------------------------
// x0 prep with LDS transpose: normalize pairs, bf16 channels-last padded.
// Block: 64-px chunk x 128 ch of one batch image.
// ---------------------------------------------------------------------------
__global__ __launch_bounds__(256) void xprep_kernel(
    const float* __restrict__ x, u16* __restrict__ xbf)
{
    __shared__ float s_t[128][65];
    const int b  = blockIdx.y;
    const int p0 = blockIdx.x * 64;
    const int tid = threadIdx.x;
    for (int it = 0; it < 32; ++it) {
        int idx = it*256 + tid;
        int ch = idx >> 6, p = idx & 63;
        s_t[ch][p] = x[((size_t)b*128 + ch)*HWSZ + p0 + p];
    }
    __syncthreads();
    for (int it = 0; it < 32; ++it) {
        int idx = it*256 + tid;
        int ch = idx & 127, p = idx >> 7;
        int pix = p0 + p;
        int py = pix / 96, px = pix - py*96;
        float v0 = s_t[ch & 126][p], v1 = s_t[ch | 1][p];
        float sc = 1.f / fmaxf(sqrtf(v0*v0 + v1*v1), 1e-12f);
        float mine = (ch & 1) ? v1 : v0;
        xbf[((size_t)b*PADA + (py+3)*PADW + (px+3))*128 + ch] = f2bf(mine * sc);
    }
}

// ---------------------------------------------------------------------------
// Zero the halo pads of both bf16 state buffers.
// ---------------------------------------------------------------------------
__global__ __launch_bounds__(256) void padzero_kernel(
    u16* __restrict__ xbfA, u16* __restrict__ xbfB)
{
    const int p  = blockIdx.x;             // 0..10403
    const int py = p / PADW, px = p - py*PADW;
    if (py >= 3 && py < 99 && px >= 3 && px < 99) return;
    const int tid = threadIdx.x;
    u16* base = (tid >= 128) ? xbfB : xbfA;
    int  t    = tid & 127;
    int  b    = t >> 4;                    // 0..7
    int  ck   = t & 15;                    // 16B chunk
    u32x4 z = {0,0,0,0};
    *(u32x4*)(base + ((size_t)b*PADA + p)*128 + ck*8) = z;
}

// ---------------------------------------------------------------------------
// Fused implicit-GEMM conv (bf16 MFMA) + Kuramoto step + energy.
// Tile 12x8 px x 128 oc, 4 waves (2M x 2N), input-stationary A halo
// (18x14x64ch per half), B double-buffered with counted vmcnt, one
// barrier per tap.
// ---------------------------------------------------------------------------
template<bool CGN>
__global__ __launch_bounds__(256, 2) void convk(
    const u16*   __restrict__ xbf_in,
    const u16*   __restrict__ wbf,
    const u32*   __restrict__ cgn,
    const float* __restrict__ craw,
    const float* __restrict__ cb,
    const float* __restrict__ gnw, const float* __restrict__ gnb,
    const float* __restrict__ stats,
    const float* __restrict__ omega,
    float* __restrict__ xout, u16* __restrict__ xbf_out,
    float* __restrict__ es, int write_bf)
{
    __shared__ __align__(16) u16 s_a[16128];        // 252 plin x 64 ch
    __shared__ __align__(16) u16 s_b[2][8192];      // 128 oc x 64 ch, dbuf

    const int tid = threadIdx.x;
    const int w   = tid >> 6, l = tid & 63;
    const int b   = blockIdx.y;
    const int bx  = blockIdx.x;            // 0..95
    const int tpy = bx / 12;               // 12-row band
    const int tpx = bx - tpy*12;           // 8-col band
    const int wm  = w >> 1, wn = w & 1;
    const int l15 = l & 15, l4 = l >> 4;

    // fragment base offsets
    int pb[3];
    #pragma unroll
    for (int mi = 0; mi < 3; ++mi) {
        int m = wm*48 + mi*16 + l15;
        pb[mi] = (m >> 3)*14 + (m & 7);
    }
    int boff[4];
    #pragma unroll
    for (int ni = 0; ni < 4; ++ni) {
        int oc = wn*64 + ni*16 + l15;
        boff[ni] = oc*64 + ((l4 ^ (oc & 7)) << 3);
    }

    f32x4 acc[3][4] = {};

    const size_t img_base = (size_t)b * PADA;

    for (int h = 0; h < 2; ++h) {
        __builtin_amdgcn_s_barrier();      // all waves done with s_a / s_b
        // ---- stage A halo: 252 plin x 64 ch (this half) ----
        #pragma unroll 1
        for (int it = 0; it < 8; ++it) {
            int i = it*256 + tid;
            if (i < 2016) {
                int r   = i / 112;
                int rem = i - r*112;
                int px  = rem >> 3, g = rem & 7;
                int plin = r*14 + px;
                const u16* src = xbf_in + (img_base + (size_t)(tpy*12 + r)*PADW
                                  + tpx*8 + px)*128 + h*64 + ((g ^ (plin & 7)) << 3);
                GLD_LDS16(src, s_a + i*8);
            }
        }
        // ---- stage B tap0 -> buf0 ----
        {
            const u16* wsrc = wbf + h*64;
            #pragma unroll
            for (int it = 0; it < 4; ++it) {
                int i = it*256 + tid;
                int oc = i >> 3, g = i & 7;
                GLD_LDS16(wsrc + oc*128 + ((g ^ (oc & 7)) << 3), s_b[0] + i*8);
            }
        }
        asm volatile("s_waitcnt vmcnt(0)" ::: "memory");
        __builtin_amdgcn_sched_barrier(0);

        int tap = 0;
        #pragma unroll 1
        for (int ty = 0; ty < 7; ++ty) {
            #pragma unroll 1
            for (int tx = 0; tx < 7; ++tx) {
                __builtin_amdgcn_s_barrier();   // buf[(tap+1)&1] free, A/B visible
                const int nt = tap + 1;
                if (nt < 49) {
                    const u16* wsrc = wbf + (size_t)nt*16384 + h*64;
                    u16* dst = s_b[nt & 1];
                    #pragma unroll
                    for (int it = 0; it < 4; ++it) {
                        int i = it*256 + tid;
                        int oc = i >> 3, g = i & 7;
                        GLD_LDS16(wsrc + oc*128 + ((g ^ (oc & 7)) << 3), dst + i*8);
                    }
                    asm volatile("s_waitcnt vmcnt(4)" ::: "memory");
                } else {
                    asm volatile("s_waitcnt vmcnt(0)" ::: "memory");
                }
                __builtin_amdgcn_sched_barrier(0);

                __builtin_amdgcn_s_setprio(1);
                const int pdel = ty*14 + tx;
                const u16* sb = s_b[tap & 1];
                bf16x8 afA[3], afB[3], bfA[4], bfB[4];
                #pragma unroll
                for (int mi = 0; mi < 3; ++mi) {
                    int plin = pb[mi] + pdel;
                    int a0 = plin*64 + ((l4 ^ (plin & 7)) << 3);
                    afA[mi] = *(const bf16x8*)(s_a + a0);
                    afB[mi] = *(const bf16x8*)(s_a + (a0 ^ 32));
                }
                #pragma unroll
                for (int ni = 0; ni < 4; ++ni) {
                    bfA[ni] = *(const bf16x8*)(sb + boff[ni]);
                    bfB[ni] = *(const bf16x8*)(sb + (boff[ni] ^ 32));
                }
                #pragma unroll
                for (int mi = 0; mi < 3; ++mi)
                    #pragma unroll
                    for (int ni = 0; ni < 4; ++ni)
                        acc[mi][ni] = __builtin_amdgcn_mfma_f32_16x16x32_bf16(
                            afA[mi], bfA[ni], acc[mi][ni], 0, 0, 0);
                #pragma unroll
                for (int mi = 0; mi < 3; ++mi)
                    #pragma unroll
                    for (int ni = 0; ni < 4; ++ni)
                        acc[mi][ni] = __builtin_amdgcn_mfma_f32_16x16x32_bf16(
                            afB[mi], bfB[ni], acc[mi][ni], 0, 0, 0);
                __builtin_amdgcn_s_setprio(0);
                ++tap;
            }
        }
    }

    // ---- epilogue ----
    const float om = omega[0];
    const size_t nb = (size_t)b * (CCH*HWSZ);
    float esum = 0.f;

    #pragma unroll
    for (int mi = 0; mi < 3; ++mi) {
        const int m   = wm*48 + mi*16 + l4*4;
        const int py  = tpy*12 + (m >> 3);
        const int px0 = tpx*8 + (m & 7);
        const int pix = py*96 + px0;
        #pragma unroll
        for (int ni = 0; ni < 4; ++ni) {
            const int oc = wn*64 + ni*16 + l15;
            const int g  = oc >> 1;
            f32x4 cv;
            if (CGN) {
                u32x4 cg4 = *(const u32x4*)(cgn + (size_t)(b*64+g)*HWSZ + pix);
                #pragma unroll
                for (int j = 0; j < 4; ++j)
                    cv[j] = bf2f((oc & 1) ? (u16)(cg4[j] >> 16) : (u16)(cg4[j] & 0xffff));
            } else {
                const float mu = stats[(b*64+g)*2], rs = stats[(b*64+g)*2+1];
                const float gw = gnw[oc];
                const float wsc = gw*rs, bsc = gnb[oc] - mu*rs*gw + cb[oc];
                f32x4 c4 = *(const f32x4*)(craw + nb + (size_t)oc*HWSZ + pix);
                #pragma unroll
                for (int j = 0; j < 4; ++j) cv[j] = fmaf(c4[j], wsc, bsc);
            }
            f32x4 out4;
            #pragma unroll
            for (int j = 0; j < 4; ++j) {
                u32 xv = *(const u32*)(xbf_in + (img_base + (size_t)(py+3)*PADW
                             + (px0 + j + 3))*128 + (oc & 126));
                float x0 = bf2f((u16)(xv & 0xffff));
                float x1 = bf2f((u16)(xv >> 16));
                float xo = (oc & 1) ? x1 : x0;
                float xp = (oc & 1) ? x0 : x1;
                float yo = acc[mi][ni][j] + cv[j];
                float yp = __shfl_xor(yo, 1);
                float inner = xo*yo + xp*yp;
                esum += inner;
                float rot  = (oc & 1) ?  xp : -xp;
                float rotp = (oc & 1) ? -xo :  xo;
                float xn  = xo + om*rot  + (yo - inner*xo);
                float xnp = xp + om*rotp + (yp - inner*xp);
                float sc2 = 1.f / fmaxf(sqrtf(xn*xn + xnp*xnp), 1e-12f);
                out4[j] = xn * sc2;
            }
            *(f32x4*)(xout + nb + (size_t)oc*HWSZ + pix) = out4;
            if (write_bf) {
                size_t o = (img_base + (size_t)(py+3)*PADW + (px0+3))*128 + oc;
                #pragma unroll
                for (int j = 0; j < 4; ++j)
                    xbf_out[o + (size_t)j*128] = f2bf(out4[j]);
            }
        }
    }

    // energy reduction (reuse s_b as scratch)
    __syncthreads();
    float* s_red = (float*)s_b;
    s_red[tid] = esum;
    __syncthreads();
    for (int s = 128; s > 0; s >>= 1) {
        if (tid < s) s_red[tid] += s_red[tid + s];
        __syncthreads();
    }
    if (tid == 0) atomicAdd(es + b, -0.5f * s_red[0]);
}

// ---------------------------------------------------------------------------
// Fallback (fp32 VALU path) if ws too small.
// ---------------------------------------------------------------------------
template<bool FIRST>
__global__ __launch_bounds__(256) void conv_kur_kernel(
    const float* __restrict__ xin, const float* __restrict__ craw,
    const float* __restrict__ cw, const float* __restrict__ cb,
    const float* __restrict__ gnw, const float* __restrict__ gnb,
    const float* __restrict__ omega, const float* __restrict__ stats,
    float* __restrict__ xout, float* __restrict__ es)
{
    __shared__ float s_in[2][22][24];
    __shared__ float s_w[2][49][16];
    __shared__ float s_red[256];
    const int tid = threadIdx.x;
    const int tile = blockIdx.x, ocb = blockIdx.y, b = blockIdx.z;
    const int row0 = (tile / 6) * 16, col0 = (tile % 6) * 16;
    const int pxg = tid & 63, ocg = tid >> 6;
    const int ry = pxg >> 2, sx = pxg & 3;
    const size_t in_base = (size_t)b * CCH * HWSZ;
    float acc[4][4] = {};
    for (int icp = 0; icp < 64; ++icp) {
        __syncthreads();
        for (int idx = tid; idx < 968; idx += 256) {
            int ch = idx / 484, rem = idx - ch*484;
            int r = rem / 22, cl = rem - r*22;
            int gr = row0 + r - 3, gc = col0 + cl - 3;
            float v = 0.f;
            if (gr >= 0 && gr < IMG_H && gc >= 0 && gc < IMG_W)
                v = xin[in_base + (size_t)(icp*2 + ch)*HWSZ + gr*IMG_W + gc];
            s_in[ch][r][cl] = v;
        }
        {
            int combo = tid & 31, q = tid >> 5;
            if (q < 7) {
                int ch = combo >> 4, j = combo & 15;
                const float* wp = cw + ((size_t)(ocb*16 + j)*CCH + icp*2 + ch)*49 + q*7;
                #pragma unroll
                for (int t7 = 0; t7 < 7; ++t7) s_w[ch][q*7 + t7][j] = wp[t7];
            }
        }
        __syncthreads();
        if (FIRST) {
            for (int idx = tid; idx < 484; idx += 256) {
                int r = idx / 22, cl = idx - r*22;
                float v0 = s_in[0][r][cl], v1 = s_in[1][r][cl];
                float sc = 1.f / fmaxf(sqrtf(v0*v0 + v1*v1), 1e-12f);
                s_in[0][r][cl] = v0*sc; s_in[1][r][cl] = v1*sc;
            }
            __syncthreads();
        }
        #pragma unroll
        for (int ch = 0; ch < 2; ++ch)
            #pragma unroll
            for (int dy = 0; dy < 7; ++dy) {
                float r[12];
                const float* rp = &s_in[ch][ry + dy][sx*4];
                #pragma unroll
                for (int i = 0; i < 12; ++i) r[i] = rp[i];
                #pragma unroll
                for (int dx = 0; dx < 7; ++dx) {
                    const float* wv = &s_w[ch][dy*7 + dx][ocg*4];
                    float w0 = wv[0], w1 = wv[1], w2 = wv[2], w3 = wv[3];
                    #pragma unroll
                    for (int p = 0; p < 4; ++p) {
                        float iv = r[dx + p];
                        acc[0][p] = fmaf(w0, iv, acc[0][p]);
                        acc[1][p] = fmaf(w1, iv, acc[1][p]);
                        acc[2][p] = fmaf(w2, iv, acc[2][p]);
                        acc[3][p] = fmaf(w3, iv, acc[3][p]);
                    }
                }
            }
    }
    const int py = row0 + ry, px0 = col0 + sx*4;
    const float om = omega[0];
    const int ocbase = ocb*16 + ocg*4;
    float esum = 0.f;
    #pragma unroll
    for (int pr = 0; pr < 2; ++pr) {
        const int oc0 = ocbase + pr*2;
        const int g = oc0 >> 1;
        const float mu = stats[(b*64+g)*2], rs = stats[(b*64+g)*2+1];
        const float w0s = gnw[oc0]*rs,   b0s = gnb[oc0]   - mu*rs*gnw[oc0];
        const float w1s = gnw[oc0+1]*rs, b1s = gnb[oc0+1] - mu*rs*gnw[oc0+1];
        const float cb0 = cb[oc0], cb1 = cb[oc0+1];
        const size_t off = in_base + (size_t)oc0*HWSZ + py*IMG_W + px0;
        const float* c0p = craw + off; const float* c1p = c0p + HWSZ;
        const float* x0p = xin  + off; const float* x1p = x0p + HWSZ;
        float* o0p = xout + off; float* o1p = o0p + HWSZ;
        #pragma unroll
        for (int p = 0; p < 4; ++p) {
            float x0 = x0p[p], x1 = x1p[p];
            if (FIRST) {
                float sc = 1.f / fmaxf(sqrtf(x0*x0 + x1*x1), 1e-12f);
                x0 *= sc; x1 *= sc;
            }
            float y0 = acc[pr*2][p]   + cb0 + fmaf(c0p[p], w0s, b0s);
            float y1 = acc[pr*2+1][p] + cb1 + fmaf(c1p[p], w1s, b1s);
            float inner = x0*y0 + x1*y1;
            esum += inner;
            float xn0 = x0 - om*x1 + (y0 - inner*x0);
            float xn1 = x1 + om*x0 + (y1 - inner*x1);
            float sc2 = 1.f / fmaxf(sqrtf(xn0*xn0 + xn1*xn1), 1e-12f);
            o0p[p] = xn0*sc2; o1p[p] = xn1*sc2;
        }
    }
    s_red[tid] = esum;
    __syncthreads();
    for (int s = 128; s > 0; s >>= 1) {
        if (tid < s) s_red[tid] += s_red[tid + s];
        __syncthreads();
    }
    if (tid == 0) atomicAdd(es + b, -s_red[0]);
}

// ---------------------------------------------------------------------------
extern "C" void kernel_launch(void* const* d_in, const int* in_sizes, int n_in,
                              void* d_out, int out_size, void* d_ws, size_t ws_size,
                              hipStream_t stream)
{
    const float* x   = (const float*)d_in[0];
    const float* c   = (const float*)d_in[1];
    const float* cw  = (const float*)d_in[2];
    const float* cb  = (const float*)d_in[3];
    const float* gnw = (const float*)d_in[4];
    const float* gnb = (const float*)d_in[5];
    const float* om  = (const float*)d_in[6];
    float* out = (float*)d_out;

    float* stats = (float*)d_ws;
    hipMemsetAsync(out + ES_OFF, 0, 40 * sizeof(float), stream);
    gn_stats_kernel<<<512, 256, 0, stream>>>(c, stats);

    // ws layouts
    const size_t OFF_WBF = 4096;
    const size_t WBF_B   = (size_t)49*16384*2;            // 1,605,632
    const size_t OFF_CGN = OFF_WBF + WBF_B;               // 1,609,728
    const size_t CGN_B   = (size_t)8*64*HWSZ*4;           // 18,874,368
    const size_t HI_XA   = OFF_CGN + CGN_B;               // 20,484,096
    const size_t HI_XB   = HI_XA + XBF_BYTES;             // 41,791,488
    const size_t WS_HI   = HI_XB + XBF_BYTES;             // 63,098,880
    const size_t MID_XA  = OFF_CGN;                       // 1,609,728
    const size_t MID_XB  = MID_XA + XBF_BYTES;
    const size_t WS_MID  = MID_XB + XBF_BYTES;            // 44,224,512

    if (ws_size >= WS_MID) {
        const bool hi = (ws_size >= WS_HI);
        u16* wbf  = (u16*)((char*)d_ws + OFF_WBF);
        u32* cgnp = (u32*)((char*)d_ws + OFF_CGN);
        u16* xbfA = (u16*)((char*)d_ws + (hi ? HI_XA : MID_XA));
        u16* xbfB = (u16*)((char*)d_ws + (hi ? HI_XB : MID_XB));

        wprep_kernel<<<(128*128*49 + 255)/256, 256, 0, stream>>>(cw, wbf);
        if (hi)
            cprep_kernel<<<dim3(9, 512), 256, 0, stream>>>(c, stats, gnw, gnb, cb, cgnp);
        xprep_kernel<<<dim3(144, 8), 256, 0, stream>>>(x, xbfA);
        padzero_kernel<<<PADA, 256, 0, stream>>>(xbfA, xbfB);

        dim3 grid(96, 8);
        u16* xin  = xbfA;
        u16* xalt = xbfB;
        for (int t = 0; t < NT; ++t) {
            float* xo  = out + (size_t)t * XS_ELEMS;
            float* esl = out + ES_OFF + (t + 1) * 8;
            int wb = (t < NT-1) ? 1 : 0;
            if (hi)
                convk<true><<<grid, 256, 0, stream>>>(xin, wbf, cgnp, c, cb, gnw,
                    gnb, stats, om, xo, xalt, esl, wb);
            else
                convk<false><<<grid, 256, 0, stream>>>(xin, wbf, cgnp, c, cb, gnw,
                    gnb, stats, om, xo, xalt, esl, wb);
            u16* tmp = xin; xin = xalt; xalt = tmp;
        }
    } else {
        dim3 grid(36, 8, 8);
        const float* xin = x;
        for (int t = 0; t < NT; ++t) {
            float* xo  = out + (size_t)t * XS_ELEMS;
            float* esl = out + ES_OFF + (t + 1) * 8;
            if (t == 0)
                conv_kur_kernel<true ><<<grid, 256, 0, stream>>>(xin, c, cw, cb, gnw, gnb, om, stats, xo, esl);
            else
                conv_kur_kernel<false><<<grid, 256, 0, stream>>>(xin, c, cw, cb, gnw, gnb, om, stats, xo, esl);
            xin = xo;
        }
    }
}

// Round 4
// 527.157 us; speedup vs baseline: 1.6556x; 1.6556x over previous
//
#include <hip/hip_runtime.h>
#include <math.h>

typedef unsigned short u16;
typedef unsigned int   u32;
typedef unsigned char  u8;
typedef __attribute__((ext_vector_type(4))) float f32x4;
typedef __attribute__((ext_vector_type(4))) u32   u32x4;
typedef __attribute__((ext_vector_type(8))) int   i32x8;
typedef __attribute__((ext_vector_type(4))) int   i32x4;

#define IMG_W 96
#define IMG_H 96
#define HWSZ  9216
#define CCH   128
#define BATCH 8
#define NT    4

#define PADW  102
#define PADA  (102*102)
#define XQ_BYTES ((size_t)BATCH*PADA*128)      // 10,653,696 (fp8 state)

#define XS_ELEMS (BATCH*CCH*HWSZ)
#define ES_OFF   (4*XS_ELEMS)

__device__ inline u16 f2bf(float f) {
    u32 u = __float_as_uint(f);
    u += 0x7fffu + ((u >> 16) & 1u);
    return (u16)(u >> 16);
}
__device__ inline float bf2f(u16 h) { return __uint_as_float(((u32)h) << 16); }

#define GLD_LDS16(g, l) \
    __builtin_amdgcn_global_load_lds((const __attribute__((address_space(1))) void*)(g), \
                                     (__attribute__((address_space(3))) void*)(l), 16, 0, 0)

// ---------------------------------------------------------------------------
// GroupNorm stats: one block per (b, group of 2 ch) -> (mu, rstd)
// ---------------------------------------------------------------------------
__global__ __launch_bounds__(256) void gn_stats_kernel(
    const float* __restrict__ c, float* __restrict__ stats)
{
    const int bg  = blockIdx.x;
    const int tid = threadIdx.x;
    const float4* p4 = (const float4*)(c + (size_t)bg * 18432);
    float s1 = 0.f, s2 = 0.f;
    for (int i = tid; i < 18432/4; i += 256) {
        float4 v = p4[i];
        s1 += v.x + v.y + v.z + v.w;
        s2 += v.x*v.x + v.y*v.y + v.z*v.z + v.w*v.w;
    }
    __shared__ float r1[256], r2[256];
    r1[tid] = s1; r2[tid] = s2;
    __syncthreads();
    for (int s = 128; s > 0; s >>= 1) {
        if (tid < s) { r1[tid] += r1[tid+s]; r2[tid] += r2[tid+s]; }
        __syncthreads();
    }
    if (tid == 0) {
        float mu  = r1[0] * (1.f/18432.f);
        float var = fmaxf(r2[0] * (1.f/18432.f) - mu*mu, 0.f);
        stats[bg*2]   = mu;
        stats[bg*2+1] = rsqrtf(var + 1e-5f);
    }
}

// ---------------------------------------------------------------------------
// Weight prep: conv_w f32 [oc][ic][7][7] -> wq fp8 e4m3 [tap][oc][ic]
// One thread per (tap, oc, ic-quad): 4 strided f32 reads, one u32 write.
// ---------------------------------------------------------------------------
__global__ __launch_bounds__(256) void wprep_kernel(
    const float* __restrict__ cw, u32* __restrict__ wq)
{
    int idx = blockIdx.x * 256 + threadIdx.x;      // < 49*128*32 = 200704
    if (idx >= 200704) return;
    int ic4 = idx & 31;
    int rem = idx >> 5;
    int oc  = rem & 127;
    int tap = rem >> 7;
    const float* s = cw + ((size_t)oc*128 + ic4*4)*49 + tap;
    float v0 = s[0], v1 = s[49], v2 = s[98], v3 = s[147];
    u32 lo = __builtin_amdgcn_cvt_pk_fp8_f32(v0, v1, 0, false);
    u32 pk = __builtin_amdgcn_cvt_pk_fp8_f32(v2, v3, lo, true);
    wq[(size_t)tap*4096 + oc*32 + ic4] = pk;
}

// ---------------------------------------------------------------------------
// cgn prep: GN-affine(c) + conv bias, packed bf16 pairs, planar per group.
// ---------------------------------------------------------------------------
__global__ __launch_bounds__(256) void cprep_kernel(
    const float* __restrict__ c, const float* __restrict__ stats,
    const float* __restrict__ gnw, const float* __restrict__ gnb,
    const float* __restrict__ cb, u32* __restrict__ cgn)
{
    const int bg  = blockIdx.y;            // b*64+g
    const int pix = blockIdx.x * 1024 + threadIdx.x * 4;
    const int b   = bg >> 6, g = bg & 63;
    const int ch0 = 2*g, ch1 = 2*g + 1;
    const float mu = stats[bg*2], rs = stats[bg*2+1];
    const float w0 = gnw[ch0]*rs, b0 = gnb[ch0] - mu*w0 + cb[ch0];
    const float w1 = gnw[ch1]*rs, b1 = gnb[ch1] - mu*w1 + cb[ch1];
    f32x4 c0 = *(const f32x4*)(c + ((size_t)(b*128+ch0))*HWSZ + pix);
    f32x4 c1 = *(const f32x4*)(c + ((size_t)(b*128+ch1))*HWSZ + pix);
    u32x4 v;
    #pragma unroll
    for (int j = 0; j < 4; ++j)
        v[j] = (u32)f2bf(fmaf(c0[j], w0, b0)) | ((u32)f2bf(fmaf(c1[j], w1, b1)) << 16);
    *(u32x4*)(cgn + (size_t)bg*HWSZ + pix) = v;
}

// ---------------------------------------------------------------------------
// x0 prep: LDS transpose, normalize pairs, fp8 channels-last padded state.
// ---------------------------------------------------------------------------
__global__ __launch_bounds__(256) void xprep_kernel(
    const float* __restrict__ x, u8* __restrict__ xq)
{
    __shared__ float s_t[128][65];
    const int b  = blockIdx.y;
    const int p0 = blockIdx.x * 64;
    const int tid = threadIdx.x;
    for (int it = 0; it < 32; ++it) {
        int idx = it*256 + tid;
        int ch = idx >> 6, p = idx & 63;
        s_t[ch][p] = x[((size_t)b*128 + ch)*HWSZ + p0 + p];
    }
    __syncthreads();
    for (int it = 0; it < 16; ++it) {
        int idx = it*256 + tid;          // 64 px * 64 pairs
        int g = idx & 63, p = idx >> 6;
        int pix = p0 + p;
        int py = pix / 96, px = pix - py*96;
        float v0 = s_t[2*g][p], v1 = s_t[2*g+1][p];
        float sc = 1.f / fmaxf(sqrtf(v0*v0 + v1*v1), 1e-12f);
        u32 pk = __builtin_amdgcn_cvt_pk_fp8_f32(v0*sc, v1*sc, 0, false);
        *(u16*)(xq + ((size_t)b*PADA + (py+3)*PADW + (px+3))*128 + 2*g) = (u16)(pk & 0xffff);
    }
}

// ---------------------------------------------------------------------------
// Fused implicit-GEMM conv (fp8 MX MFMA, K=128 per instr) + Kuramoto + energy.
// 384 thr = 6 waves (3M x 2N); tile 144 px (12x12) x 128 oc; wave 48x64.
// A halo (18x18x128B) staged once; B double-buffered, prefetch-then-compute,
// one __syncthreads per tap (its vmcnt(0) drain is free: loads fly a full tap).
// ---------------------------------------------------------------------------
__global__ __launch_bounds__(384, 3) void convk8(
    const u8*    __restrict__ xq_in,
    const u8*    __restrict__ wq,
    const u32*   __restrict__ cgn,
    const float* __restrict__ omega,
    float* __restrict__ xout, u8* __restrict__ xq_out,
    float* __restrict__ es, int write_q)
{
    __shared__ __align__(16) u8 s_a[324*128];     // 41472 B
    __shared__ __align__(16) u8 s_b[2][16384];

    const int tid = threadIdx.x;
    const int w   = tid >> 6, l = tid & 63;
    const int b   = blockIdx.y;
    const int bx  = blockIdx.x;          // 0..63
    const int tpy = bx >> 3, tpx = bx & 7;
    const int wm  = w >> 1, wn = w & 1;  // wm 0..2, wn 0..1
    const int l15 = l & 15, l4 = l >> 4;

    const u8* abase = xq_in + ((size_t)b*PADA + (size_t)tpy*12*PADW + (size_t)tpx*12)*128;

    // ---- stage A halo: 324 px x 8 granules of 16B (source pre-swizzled) ----
    #pragma unroll 1
    for (int it = 0; it < 7; ++it) {
        int i = it*384 + tid;
        if (i < 2592) {
            int p = i >> 3, g = i & 7;
            int hr = p / 18, hc = p - hr*18;
            const u8* src = abase + ((size_t)hr*PADW + hc)*128 + ((g ^ (p & 7)) << 4);
            GLD_LDS16(src, s_a + i*16);
        }
    }
    // ---- stage B tap 0 ----
    #pragma unroll
    for (int it = 0; it < 3; ++it) {
        int i = it*384 + tid;
        if (i < 1024) {
            int oc = i >> 3, g = i & 7;
            GLD_LDS16(wq + oc*128 + ((g ^ (oc & 7)) << 4), s_b[0] + i*16);
        }
    }
    __syncthreads();

    // per-lane fragment pixel bases
    int pb[3];
    #pragma unroll
    for (int mi = 0; mi < 3; ++mi) {
        int m = wm*48 + mi*16 + l15;
        pb[mi] = (m/12)*18 + (m - (m/12)*12);
    }

    f32x4 acc[3][4] = {};

    int tap = 0;
    #pragma unroll 1
    for (int ty = 0; ty < 7; ++ty) {
        #pragma unroll 1
        for (int tx = 0; tx < 7; ++tx) {
            // prefetch next tap's B into the other buffer
            const int nt = tap + 1;
            if (nt < 49) {
                const u8* wsrc = wq + (size_t)nt*16384;
                u8* dst = s_b[nt & 1];
                #pragma unroll
                for (int it = 0; it < 3; ++it) {
                    int i = it*384 + tid;
                    if (i < 1024) {
                        int oc = i >> 3, g = i & 7;
                        GLD_LDS16(wsrc + oc*128 + ((g ^ (oc & 7)) << 4), dst + i*16);
                    }
                }
            }
            // fragments (fp8, 32B per operand per lane)
            const u8* sb = s_b[tap & 1];
            const int pdel = ty*18 + tx;
            i32x8 af[3], bfr[4];
            #pragma unroll
            for (int mi = 0; mi < 3; ++mi) {
                int plin = pb[mi] + pdel;
                const u8* base = s_a + plin*128;
                int sw = plin & 7;
                i32x4 lo = *(const i32x4*)(base + (((l4*2    ) ^ sw) << 4));
                i32x4 hi = *(const i32x4*)(base + (((l4*2 + 1) ^ sw) << 4));
                i32x8 v;
                v[0]=lo[0]; v[1]=lo[1]; v[2]=lo[2]; v[3]=lo[3];
                v[4]=hi[0]; v[5]=hi[1]; v[6]=hi[2]; v[7]=hi[3];
                af[mi] = v;
            }
            #pragma unroll
            for (int ni = 0; ni < 4; ++ni) {
                int oc = wn*64 + ni*16 + l15;
                const u8* base = sb + oc*128;
                int sw = oc & 7;
                i32x4 lo = *(const i32x4*)(base + (((l4*2    ) ^ sw) << 4));
                i32x4 hi = *(const i32x4*)(base + (((l4*2 + 1) ^ sw) << 4));
                i32x8 v;
                v[0]=lo[0]; v[1]=lo[1]; v[2]=lo[2]; v[3]=lo[3];
                v[4]=hi[0]; v[5]=hi[1]; v[6]=hi[2]; v[7]=hi[3];
                bfr[ni] = v;
            }
            __builtin_amdgcn_s_setprio(1);
            #pragma unroll
            for (int mi = 0; mi < 3; ++mi)
                #pragma unroll
                for (int ni = 0; ni < 4; ++ni)
                    acc[mi][ni] = __builtin_amdgcn_mfma_scale_f32_16x16x128_f8f6f4(
                        af[mi], bfr[ni], acc[mi][ni], 0, 0, 0, 0x7F, 0, 0x7F);
            __builtin_amdgcn_s_setprio(0);
            __syncthreads();               // drains vmcnt(0) (free) + barrier
            ++tap;
        }
    }

    // ---- epilogue: Kuramoto update ----
    const float om = omega[0];
    const size_t nb = (size_t)b * (CCH*HWSZ);
    float esum = 0.f;

    #pragma unroll
    for (int mi = 0; mi < 3; ++mi) {
        const int mb  = wm*48 + mi*16 + l4*4;
        const int pr  = mb/12, pc = mb - pr*12;
        const int py  = tpy*12 + pr;
        const int px0 = tpx*12 + pc;
        const int pix = py*96 + px0;
        #pragma unroll
        for (int ni = 0; ni < 4; ++ni) {
            const int oc = wn*64 + ni*16 + l15;
            const int g  = oc >> 1;
            const u32x4 cg4 = *(const u32x4*)(cgn + (size_t)(b*64+g)*HWSZ + pix);
            const u8* xrow = xq_in + ((size_t)b*PADA + (size_t)(py+3)*PADW + (px0+3))*128 + (oc & 126);
            f32x4 out4;
            #pragma unroll
            for (int j = 0; j < 4; ++j) {
                int xv = (int)*(const u16*)(xrow + j*128);
                float x0 = __builtin_amdgcn_cvt_f32_fp8(xv, 0);
                float x1 = __builtin_amdgcn_cvt_f32_fp8(xv, 1);
                float xo = (oc & 1) ? x1 : x0;
                float xp = (oc & 1) ? x0 : x1;
                float cv = bf2f((oc & 1) ? (u16)(cg4[j] >> 16) : (u16)(cg4[j] & 0xffff));
                float yo = acc[mi][ni][j] + cv;
                float yp = __shfl_xor(yo, 1);
                float inner = xo*yo + xp*yp;
                esum += inner;
                float rot  = (oc & 1) ?  xp : -xp;
                float rotp = (oc & 1) ? -xo :  xo;
                float xn  = xo + om*rot  + (yo - inner*xo);
                float xnp = xp + om*rotp + (yp - inner*xp);
                float sc2 = 1.f / fmaxf(sqrtf(xn*xn + xnp*xnp), 1e-12f);
                out4[j] = xn * sc2;
            }
            *(f32x4*)(xout + nb + (size_t)oc*HWSZ + pix) = out4;
            if (write_q) {
                u8* qrow = xq_out + ((size_t)b*PADA + (size_t)(py+3)*PADW + (px0+3))*128 + oc;
                #pragma unroll
                for (int j = 0; j < 4; ++j) {
                    u32 pk = __builtin_amdgcn_cvt_pk_fp8_f32(out4[j], 0.f, 0, false);
                    qrow[(size_t)j*128] = (u8)(pk & 0xff);
                }
            }
        }
    }

    // ---- energy: block reduce (reuse s_b), one atomic per block ----
    __syncthreads();
    float* s_red = (float*)s_b;
    s_red[tid] = esum;
    __syncthreads();
    if (tid < 128) s_red[tid] += s_red[tid+128] + s_red[tid+256];
    __syncthreads();
    for (int s = 64; s > 0; s >>= 1) {
        if (tid < s) s_red[tid] += s_red[tid+s];
        __syncthreads();
    }
    if (tid == 0) atomicAdd(es + b, -0.5f * s_red[0]);
}

// ---------------------------------------------------------------------------
// Fallback (fp32 VALU path) if ws too small.
// ---------------------------------------------------------------------------
template<bool FIRST>
__global__ __launch_bounds__(256) void conv_kur_kernel(
    const float* __restrict__ xin, const float* __restrict__ craw,
    const float* __restrict__ cw, const float* __restrict__ cb,
    const float* __restrict__ gnw, const float* __restrict__ gnb,
    const float* __restrict__ omega, const float* __restrict__ stats,
    float* __restrict__ xout, float* __restrict__ es)
{
    __shared__ float s_in[2][22][24];
    __shared__ float s_w[2][49][16];
    __shared__ float s_red[256];
    const int tid = threadIdx.x;
    const int tile = blockIdx.x, ocb = blockIdx.y, b = blockIdx.z;
    const int row0 = (tile / 6) * 16, col0 = (tile % 6) * 16;
    const int pxg = tid & 63, ocg = tid >> 6;
    const int ry = pxg >> 2, sx = pxg & 3;
    const size_t in_base = (size_t)b * CCH * HWSZ;
    float acc[4][4] = {};
    for (int icp = 0; icp < 64; ++icp) {
        __syncthreads();
        for (int idx = tid; idx < 968; idx += 256) {
            int ch = idx / 484, rem = idx - ch*484;
            int r = rem / 22, cl = rem - r*22;
            int gr = row0 + r - 3, gc = col0 + cl - 3;
            float v = 0.f;
            if (gr >= 0 && gr < IMG_H && gc >= 0 && gc < IMG_W)
                v = xin[in_base + (size_t)(icp*2 + ch)*HWSZ + gr*IMG_W + gc];
            s_in[ch][r][cl] = v;
        }
        {
            int combo = tid & 31, q = tid >> 5;
            if (q < 7) {
                int ch = combo >> 4, j = combo & 15;
                const float* wp = cw + ((size_t)(ocb*16 + j)*CCH + icp*2 + ch)*49 + q*7;
                #pragma unroll
                for (int t7 = 0; t7 < 7; ++t7) s_w[ch][q*7 + t7][j] = wp[t7];
            }
        }
        __syncthreads();
        if (FIRST) {
            for (int idx = tid; idx < 484; idx += 256) {
                int r = idx / 22, cl = idx - r*22;
                float v0 = s_in[0][r][cl], v1 = s_in[1][r][cl];
                float sc = 1.f / fmaxf(sqrtf(v0*v0 + v1*v1), 1e-12f);
                s_in[0][r][cl] = v0*sc; s_in[1][r][cl] = v1*sc;
            }
            __syncthreads();
        }
        #pragma unroll
        for (int ch = 0; ch < 2; ++ch)
            #pragma unroll
            for (int dy = 0; dy < 7; ++dy) {
                float r[12];
                const float* rp = &s_in[ch][ry + dy][sx*4];
                #pragma unroll
                for (int i = 0; i < 12; ++i) r[i] = rp[i];
                #pragma unroll
                for (int dx = 0; dx < 7; ++dx) {
                    const float* wv = &s_w[ch][dy*7 + dx][ocg*4];
                    float w0 = wv[0], w1 = wv[1], w2 = wv[2], w3 = wv[3];
                    #pragma unroll
                    for (int p = 0; p < 4; ++p) {
                        float iv = r[dx + p];
                        acc[0][p] = fmaf(w0, iv, acc[0][p]);
                        acc[1][p] = fmaf(w1, iv, acc[1][p]);
                        acc[2][p] = fmaf(w2, iv, acc[2][p]);
                        acc[3][p] = fmaf(w3, iv, acc[3][p]);
                    }
                }
            }
    }
    const int py = row0 + ry, px0 = col0 + sx*4;
    const float om = omega[0];
    const int ocbase = ocb*16 + ocg*4;
    float esum = 0.f;
    #pragma unroll
    for (int pr = 0; pr < 2; ++pr) {
        const int oc0 = ocbase + pr*2;
        const int g = oc0 >> 1;
        const float mu = stats[(b*64+g)*2], rs = stats[(b*64+g)*2+1];
        const float w0s = gnw[oc0]*rs,   b0s = gnb[oc0]   - mu*rs*gnw[oc0];
        const float w1s = gnw[oc0+1]*rs, b1s = gnb[oc0+1] - mu*rs*gnw[oc0+1];
        const float cb0 = cb[oc0], cb1 = cb[oc0+1];
        const size_t off = in_base + (size_t)oc0*HWSZ + py*IMG_W + px0;
        const float* c0p = craw + off; const float* c1p = c0p + HWSZ;
        const float* x0p = xin  + off; const float* x1p = x0p + HWSZ;
        float* o0p = xout + off; float* o1p = o0p + HWSZ;
        #pragma unroll
        for (int p = 0; p < 4; ++p) {
            float x0 = x0p[p], x1 = x1p[p];
            if (FIRST) {
                float sc = 1.f / fmaxf(sqrtf(x0*x0 + x1*x1), 1e-12f);
                x0 *= sc; x1 *= sc;
            }
            float y0 = acc[pr*2][p]   + cb0 + fmaf(c0p[p], w0s, b0s);
            float y1 = acc[pr*2+1][p] + cb1 + fmaf(c1p[p], w1s, b1s);
            float inner = x0*y0 + x1*y1;
            esum += inner;
            float xn0 = x0 - om*x1 + (y0 - inner*x0);
            float xn1 = x1 + om*x0 + (y1 - inner*x1);
            float sc2 = 1.f / fmaxf(sqrtf(xn0*xn0 + xn1*xn1), 1e-12f);
            o0p[p] = xn0*sc2; o1p[p] = xn1*sc2;
        }
    }
    s_red[tid] = esum;
    __syncthreads();
    for (int s = 128; s > 0; s >>= 1) {
        if (tid < s) s_red[tid] += s_red[tid + s];
        __syncthreads();
    }
    if (tid == 0) atomicAdd(es + b, -s_red[0]);
}

// ---------------------------------------------------------------------------
extern "C" void kernel_launch(void* const* d_in, const int* in_sizes, int n_in,
                              void* d_out, int out_size, void* d_ws, size_t ws_size,
                              hipStream_t stream)
{
    const float* x   = (const float*)d_in[0];
    const float* c   = (const float*)d_in[1];
    const float* cw  = (const float*)d_in[2];
    const float* cb  = (const float*)d_in[3];
    const float* gnw = (const float*)d_in[4];
    const float* gnb = (const float*)d_in[5];
    const float* om  = (const float*)d_in[6];
    float* out = (float*)d_out;

    float* stats = (float*)d_ws;
    hipMemsetAsync(out + ES_OFF, 0, 40 * sizeof(float), stream);
    gn_stats_kernel<<<512, 256, 0, stream>>>(c, stats);

    const size_t OFF_WQ  = 4096;
    const size_t OFF_CGN = OFF_WQ  + 802816;     //   806,912
    const size_t OFF_XQA = OFF_CGN + 18874368;   // 19,681,280
    const size_t OFF_XQB = OFF_XQA + XQ_BYTES;   // 30,334,976
    const size_t WS_NEED = OFF_XQB + XQ_BYTES;   // 40,988,672

    if (ws_size >= WS_NEED) {
        u32* wq   = (u32*)((char*)d_ws + OFF_WQ);
        u32* cgnp = (u32*)((char*)d_ws + OFF_CGN);
        u8*  xqA  = (u8*) ((char*)d_ws + OFF_XQA);
        u8*  xqB  = (u8*) ((char*)d_ws + OFF_XQB);

        hipMemsetAsync(xqA, 0, XQ_BYTES, stream);
        hipMemsetAsync(xqB, 0, XQ_BYTES, stream);
        wprep_kernel<<<(200704 + 255)/256, 256, 0, stream>>>(cw, wq);
        cprep_kernel<<<dim3(9, 512), 256, 0, stream>>>(c, stats, gnw, gnb, cb, cgnp);
        xprep_kernel<<<dim3(144, 8), 256, 0, stream>>>(x, xqA);

        dim3 grid(64, 8);
        u8* xin  = xqA;
        u8* xalt = xqB;
        for (int t = 0; t < NT; ++t) {
            float* xo  = out + (size_t)t * XS_ELEMS;
            float* esl = out + ES_OFF + (t + 1) * 8;
            int wb = (t < NT-1) ? 1 : 0;
            convk8<<<grid, 384, 0, stream>>>((const u8*)xin, (const u8*)wq, cgnp,
                                             om, xo, xalt, esl, wb);
            u8* tmp = xin; xin = xalt; xalt = tmp;
        }
    } else {
        dim3 grid(36, 8, 8);
        const float* xin = x;
        for (int t = 0; t < NT; ++t) {
            float* xo  = out + (size_t)t * XS_ELEMS;
            float* esl = out + ES_OFF + (t + 1) * 8;
            if (t == 0)
                conv_kur_kernel<true ><<<grid, 256, 0, stream>>>(xin, c, cw, cb, gnw, gnb, om, stats, xo, esl);
            else
                conv_kur_kernel<false><<<grid, 256, 0, stream>>>(xin, c, cw, cb, gnw, gnb, om, stats, xo, esl);
            xin = xo;
        }
    }
}

// Round 5
// 510.279 us; speedup vs baseline: 1.7104x; 1.0331x over previous
//
#include <hip/hip_runtime.h>
#include <math.h>

typedef unsigned short u16;
typedef unsigned int   u32;
typedef unsigned char  u8;
typedef __attribute__((ext_vector_type(4))) float f32x4;
typedef __attribute__((ext_vector_type(4))) u32   u32x4;
typedef __attribute__((ext_vector_type(8))) int   i32x8;
typedef __attribute__((ext_vector_type(4))) int   i32x4;

#define IMG_W 96
#define IMG_H 96
#define HWSZ  9216
#define CCH   128
#define BATCH 8
#define NT    4

#define PADW  102
#define PADA  (102*102)
#define XQ_BYTES ((size_t)BATCH*PADA*128)      // 10,653,696 (fp8 state)

#define XS_ELEMS (BATCH*CCH*HWSZ)
#define ES_OFF   (4*XS_ELEMS)

__device__ inline u16 f2bf(float f) {
    u32 u = __float_as_uint(f);
    u += 0x7fffu + ((u >> 16) & 1u);
    return (u16)(u >> 16);
}
__device__ inline float bf2f(u16 h) { return __uint_as_float(((u32)h) << 16); }

#define GLD_LDS16(g, l) \
    __builtin_amdgcn_global_load_lds((const __attribute__((address_space(1))) void*)(g), \
                                     (__attribute__((address_space(3))) void*)(l), 16, 0, 0)

// ---------------------------------------------------------------------------
// GroupNorm stats: one block per (b, group of 2 ch) -> (mu, rstd)
// ---------------------------------------------------------------------------
__global__ __launch_bounds__(256) void gn_stats_kernel(
    const float* __restrict__ c, float* __restrict__ stats)
{
    const int bg  = blockIdx.x;
    const int tid = threadIdx.x;
    const float4* p4 = (const float4*)(c + (size_t)bg * 18432);
    float s1 = 0.f, s2 = 0.f;
    for (int i = tid; i < 18432/4; i += 256) {
        float4 v = p4[i];
        s1 += v.x + v.y + v.z + v.w;
        s2 += v.x*v.x + v.y*v.y + v.z*v.z + v.w*v.w;
    }
    __shared__ float r1[256], r2[256];
    r1[tid] = s1; r2[tid] = s2;
    __syncthreads();
    for (int s = 128; s > 0; s >>= 1) {
        if (tid < s) { r1[tid] += r1[tid+s]; r2[tid] += r2[tid+s]; }
        __syncthreads();
    }
    if (tid == 0) {
        float mu  = r1[0] * (1.f/18432.f);
        float var = fmaxf(r2[0] * (1.f/18432.f) - mu*mu, 0.f);
        stats[bg*2]   = mu;
        stats[bg*2+1] = rsqrtf(var + 1e-5f);
    }
}

// ---------------------------------------------------------------------------
// Weight prep: conv_w f32 [oc][ic][7][7] -> wq fp8 e4m3 [tap][oc][ic]
// ---------------------------------------------------------------------------
__global__ __launch_bounds__(256) void wprep_kernel(
    const float* __restrict__ cw, u32* __restrict__ wq)
{
    int idx = blockIdx.x * 256 + threadIdx.x;      // < 49*128*32 = 200704
    if (idx >= 200704) return;
    int ic4 = idx & 31;
    int rem = idx >> 5;
    int oc  = rem & 127;
    int tap = rem >> 7;
    const float* s = cw + ((size_t)oc*128 + ic4*4)*49 + tap;
    float v0 = s[0], v1 = s[49], v2 = s[98], v3 = s[147];
    u32 lo = __builtin_amdgcn_cvt_pk_fp8_f32(v0, v1, 0, false);
    u32 pk = __builtin_amdgcn_cvt_pk_fp8_f32(v2, v3, lo, true);
    wq[(size_t)tap*4096 + oc*32 + ic4] = pk;
}

// ---------------------------------------------------------------------------
// cgn prep: GN-affine(c) + conv bias, packed bf16 pairs, planar per group.
// ---------------------------------------------------------------------------
__global__ __launch_bounds__(256) void cprep_kernel(
    const float* __restrict__ c, const float* __restrict__ stats,
    const float* __restrict__ gnw, const float* __restrict__ gnb,
    const float* __restrict__ cb, u32* __restrict__ cgn)
{
    const int bg  = blockIdx.y;            // b*64+g
    const int pix = blockIdx.x * 1024 + threadIdx.x * 4;
    const int b   = bg >> 6, g = bg & 63;
    const int ch0 = 2*g, ch1 = 2*g + 1;
    const float mu = stats[bg*2], rs = stats[bg*2+1];
    const float w0 = gnw[ch0]*rs, b0 = gnb[ch0] - mu*w0 + cb[ch0];
    const float w1 = gnw[ch1]*rs, b1 = gnb[ch1] - mu*w1 + cb[ch1];
    f32x4 c0 = *(const f32x4*)(c + ((size_t)(b*128+ch0))*HWSZ + pix);
    f32x4 c1 = *(const f32x4*)(c + ((size_t)(b*128+ch1))*HWSZ + pix);
    u32x4 v;
    #pragma unroll
    for (int j = 0; j < 4; ++j)
        v[j] = (u32)f2bf(fmaf(c0[j], w0, b0)) | ((u32)f2bf(fmaf(c1[j], w1, b1)) << 16);
    *(u32x4*)(cgn + (size_t)bg*HWSZ + pix) = v;
}

// ---------------------------------------------------------------------------
// x0 prep: LDS transpose, normalize pairs, fp8 channels-last padded state.
// ---------------------------------------------------------------------------
__global__ __launch_bounds__(256) void xprep_kernel(
    const float* __restrict__ x, u8* __restrict__ xq)
{
    __shared__ float s_t[128][65];
    const int b  = blockIdx.y;
    const int p0 = blockIdx.x * 64;
    const int tid = threadIdx.x;
    for (int it = 0; it < 32; ++it) {
        int idx = it*256 + tid;
        int ch = idx >> 6, p = idx & 63;
        s_t[ch][p] = x[((size_t)b*128 + ch)*HWSZ + p0 + p];
    }
    __syncthreads();
    for (int it = 0; it < 16; ++it) {
        int idx = it*256 + tid;          // 64 px * 64 pairs
        int g = idx & 63, p = idx >> 6;
        int pix = p0 + p;
        int py = pix / 96, px = pix - py*96;
        float v0 = s_t[2*g][p], v1 = s_t[2*g+1][p];
        float sc = 1.f / fmaxf(sqrtf(v0*v0 + v1*v1), 1e-12f);
        u32 pk = __builtin_amdgcn_cvt_pk_fp8_f32(v0*sc, v1*sc, 0, false);
        *(u16*)(xq + ((size_t)b*PADA + (py+3)*PADW + (px+3))*128 + 2*g) = (u16)(pk & 0xffff);
    }
}

// ---------------------------------------------------------------------------
// Fused implicit-GEMM conv (fp8 MX MFMA, K=128) + Kuramoto + energy.
// 384 thr = 6 waves (3M x 2N); tile 144 px (12x12) x 128 oc; wave 48x64.
// A halo staged once; B double-buffered via global_load_lds.
// REGISTER PIPELINE: fragments for tap t+1 are ds_read while tap t's MFMAs
// execute from the other register set -> MFMA never waits on lgkmcnt.
// One __syncthreads per tap (drains own vmcnt/lgkm, both covered by a tap).
// ---------------------------------------------------------------------------
__global__ __launch_bounds__(384, 2) void convk8(
    const u8*    __restrict__ xq_in,
    const u8*    __restrict__ wq,
    const u32*   __restrict__ cgn,
    const float* __restrict__ omega,
    float* __restrict__ xout, u8* __restrict__ xq_out,
    float* __restrict__ es, int write_q)
{
    __shared__ __align__(16) u8 s_a[324*128];     // 41472 B
    __shared__ __align__(16) u8 s_b[2][16384];

    const int tid = threadIdx.x;
    const int w   = tid >> 6, l = tid & 63;
    const int b   = blockIdx.y;
    const int bx  = blockIdx.x;          // 0..63
    const int tpy = bx >> 3, tpx = bx & 7;
    const int wm  = w >> 1, wn = w & 1;  // wm 0..2, wn 0..1
    const int l15 = l & 15, l4 = l >> 4;

    const u8* abase = xq_in + ((size_t)b*PADA + (size_t)tpy*12*PADW + (size_t)tpx*12)*128;

    // ---- stage A halo: 324 px x 8 granules of 16B (source pre-swizzled) ----
    #pragma unroll 1
    for (int it = 0; it < 7; ++it) {
        int i = it*384 + tid;
        if (i < 2592) {
            int p = i >> 3, g = i & 7;
            int hr = p / 18, hc = p - hr*18;
            const u8* src = abase + ((size_t)hr*PADW + hc)*128 + ((g ^ (p & 7)) << 4);
            GLD_LDS16(src, s_a + i*16);
        }
    }

#define ISSUE_B(k)                                                         \
    { const u8* wsrc_ = wq + (size_t)(k)*16384;                            \
      u8* dst_ = s_b[(k) & 1];                                             \
      _Pragma("unroll")                                                    \
      for (int it_ = 0; it_ < 3; ++it_) {                                  \
          int i_ = it_*384 + tid;                                          \
          if (i_ < 1024) {                                                 \
              int oc_ = i_ >> 3, g_ = i_ & 7;                              \
              GLD_LDS16(wsrc_ + oc_*128 + ((g_ ^ (oc_ & 7)) << 4),         \
                        dst_ + i_*16);                                     \
          }                                                                \
      } }

    // ---- stage B tap 0 ----
    ISSUE_B(0);
    __syncthreads();                     // A + B(0) resident

    // per-lane fragment pixel bases and LDS offsets
    int pb[3];
    #pragma unroll
    for (int mi = 0; mi < 3; ++mi) {
        int m = wm*48 + mi*16 + l15;
        pb[mi] = (m/12)*18 + (m - (m/12)*12);
    }
    int boff[4];
    #pragma unroll
    for (int ni = 0; ni < 4; ++ni) {
        int oc = wn*64 + ni*16 + l15;
        boff[ni] = oc*128 + (((l4*2) ^ (oc & 7)) << 4);
    }
    const int kloA = (l4*2) << 4;        // A k-granule byte offsets (pre-XOR)
    const int khiA = (l4*2 + 1) << 4;

#define READ_FRAGS(AF, BF, pd, sbuf)                                       \
    {                                                                      \
      _Pragma("unroll")                                                    \
      for (int mi_ = 0; mi_ < 3; ++mi_) {                                  \
          int plin_ = pb[mi_] + (pd);                                      \
          const u8* base_ = s_a + plin_*128;                               \
          int sw_ = (plin_ & 7) << 4;                                      \
          i32x4 lo_ = *(const i32x4*)(base_ + (kloA ^ sw_));               \
          i32x4 hi_ = *(const i32x4*)(base_ + (khiA ^ sw_));               \
          AF[mi_] = __builtin_shufflevector(lo_, hi_, 0,1,2,3,4,5,6,7);    \
      }                                                                    \
      _Pragma("unroll")                                                    \
      for (int ni_ = 0; ni_ < 4; ++ni_) {                                  \
          i32x4 lo_ = *(const i32x4*)((sbuf) + boff[ni_]);                 \
          i32x4 hi_ = *(const i32x4*)((sbuf) + (boff[ni_] ^ 16));          \
          BF[ni_] = __builtin_shufflevector(lo_, hi_, 0,1,2,3,4,5,6,7);    \
      } }

#define DO_MFMA(AF, BF)                                                    \
    __builtin_amdgcn_s_setprio(1);                                         \
    _Pragma("unroll")                                                      \
    for (int mi_ = 0; mi_ < 3; ++mi_)                                      \
        _Pragma("unroll")                                                  \
        for (int ni_ = 0; ni_ < 4; ++ni_)                                  \
            acc[mi_][ni_] = __builtin_amdgcn_mfma_scale_f32_16x16x128_f8f6f4( \
                AF[mi_], BF[ni_], acc[mi_][ni_], 0, 0, 0, 0x7F, 0, 0x7F);  \
    __builtin_amdgcn_s_setprio(0);

    f32x4 acc[3][4] = {};
    i32x8 a0f[3], b0f[4], a1f[3], b1f[4];

    // prologue of the register pipeline
    ISSUE_B(1);
    READ_FRAGS(a0f, b0f, 0, s_b[0]);     // frags for tap 0

    int pdN = 1, txN = 1;                // pdel/tx of the NEXT tap to read (tap 1)
    #pragma unroll 1
    for (int t = 0; t < 48; t += 2) {
        // ---- even tap t: compute set0, read set1 (tap t+1) ----
        __syncthreads();                 // B(t+1) resident; own frag reads consumed
        ISSUE_B(t+2);                    // -> s_b[t&1]
        READ_FRAGS(a1f, b1f, pdN, s_b[1]);
        if (++txN == 7) { txN = 0; pdN += 12; } else { ++pdN; }
        DO_MFMA(a0f, b0f);
        // ---- odd tap t+1: compute set1, read set0 (tap t+2) ----
        __syncthreads();
        if (t + 3 < 49) ISSUE_B(t+3);    // -> s_b[1]
        READ_FRAGS(a0f, b0f, pdN, s_b[0]);
        if (++txN == 7) { txN = 0; pdN += 12; } else { ++pdN; }
        DO_MFMA(a1f, b1f);
    }
    // ---- tap 48 ----
    __syncthreads();
    DO_MFMA(a0f, b0f);

    // ---- epilogue: Kuramoto update ----
    const float om = omega[0];
    const size_t nb = (size_t)b * (CCH*HWSZ);
    float esum = 0.f;

    #pragma unroll
    for (int mi = 0; mi < 3; ++mi) {
        const int mb  = wm*48 + mi*16 + l4*4;
        const int pr  = mb/12, pc = mb - pr*12;
        const int py  = tpy*12 + pr;
        const int px0 = tpx*12 + pc;
        const int pix = py*96 + px0;
        #pragma unroll
        for (int ni = 0; ni < 4; ++ni) {
            const int oc = wn*64 + ni*16 + l15;
            const int g  = oc >> 1;
            const u32x4 cg4 = *(const u32x4*)(cgn + (size_t)(b*64+g)*HWSZ + pix);
            const u8* xrow = xq_in + ((size_t)b*PADA + (size_t)(py+3)*PADW + (px0+3))*128 + (oc & 126);
            f32x4 out4;
            #pragma unroll
            for (int j = 0; j < 4; ++j) {
                int xv = (int)*(const u16*)(xrow + j*128);
                float x0 = __builtin_amdgcn_cvt_f32_fp8(xv, 0);
                float x1 = __builtin_amdgcn_cvt_f32_fp8(xv, 1);
                float xo = (oc & 1) ? x1 : x0;
                float xp = (oc & 1) ? x0 : x1;
                float cv = bf2f((oc & 1) ? (u16)(cg4[j] >> 16) : (u16)(cg4[j] & 0xffff));
                float yo = acc[mi][ni][j] + cv;
                float yp = __shfl_xor(yo, 1);
                float inner = xo*yo + xp*yp;
                esum += inner;
                float rot  = (oc & 1) ?  xp : -xp;
                float rotp = (oc & 1) ? -xo :  xo;
                float xn  = xo + om*rot  + (yo - inner*xo);
                float xnp = xp + om*rotp + (yp - inner*xp);
                float sc2 = 1.f / fmaxf(sqrtf(xn*xn + xnp*xnp), 1e-12f);
                out4[j] = xn * sc2;
            }
            *(f32x4*)(xout + nb + (size_t)oc*HWSZ + pix) = out4;
            if (write_q) {
                u8* qrow = xq_out + ((size_t)b*PADA + (size_t)(py+3)*PADW + (px0+3))*128 + oc;
                #pragma unroll
                for (int j = 0; j < 4; ++j) {
                    u32 pk = __builtin_amdgcn_cvt_pk_fp8_f32(out4[j], 0.f, 0, false);
                    qrow[(size_t)j*128] = (u8)(pk & 0xff);
                }
            }
        }
    }

    // ---- energy: block reduce (reuse s_b), one atomic per block ----
    __syncthreads();
    float* s_red = (float*)s_b;
    s_red[tid] = esum;
    __syncthreads();
    if (tid < 128) s_red[tid] += s_red[tid+128] + s_red[tid+256];
    __syncthreads();
    for (int s = 64; s > 0; s >>= 1) {
        if (tid < s) s_red[tid] += s_red[tid+s];
        __syncthreads();
    }
    if (tid == 0) atomicAdd(es + b, -0.5f * s_red[0]);
#undef ISSUE_B
#undef READ_FRAGS
#undef DO_MFMA
}

// ---------------------------------------------------------------------------
// Fallback (fp32 VALU path) if ws too small.
// ---------------------------------------------------------------------------
template<bool FIRST>
__global__ __launch_bounds__(256) void conv_kur_kernel(
    const float* __restrict__ xin, const float* __restrict__ craw,
    const float* __restrict__ cw, const float* __restrict__ cb,
    const float* __restrict__ gnw, const float* __restrict__ gnb,
    const float* __restrict__ omega, const float* __restrict__ stats,
    float* __restrict__ xout, float* __restrict__ es)
{
    __shared__ float s_in[2][22][24];
    __shared__ float s_w[2][49][16];
    __shared__ float s_red[256];
    const int tid = threadIdx.x;
    const int tile = blockIdx.x, ocb = blockIdx.y, b = blockIdx.z;
    const int row0 = (tile / 6) * 16, col0 = (tile % 6) * 16;
    const int pxg = tid & 63, ocg = tid >> 6;
    const int ry = pxg >> 2, sx = pxg & 3;
    const size_t in_base = (size_t)b * CCH * HWSZ;
    float acc[4][4] = {};
    for (int icp = 0; icp < 64; ++icp) {
        __syncthreads();
        for (int idx = tid; idx < 968; idx += 256) {
            int ch = idx / 484, rem = idx - ch*484;
            int r = rem / 22, cl = rem - r*22;
            int gr = row0 + r - 3, gc = col0 + cl - 3;
            float v = 0.f;
            if (gr >= 0 && gr < IMG_H && gc >= 0 && gc < IMG_W)
                v = xin[in_base + (size_t)(icp*2 + ch)*HWSZ + gr*IMG_W + gc];
            s_in[ch][r][cl] = v;
        }
        {
            int combo = tid & 31, q = tid >> 5;
            if (q < 7) {
                int ch = combo >> 4, j = combo & 15;
                const float* wp = cw + ((size_t)(ocb*16 + j)*CCH + icp*2 + ch)*49 + q*7;
                #pragma unroll
                for (int t7 = 0; t7 < 7; ++t7) s_w[ch][q*7 + t7][j] = wp[t7];
            }
        }
        __syncthreads();
        if (FIRST) {
            for (int idx = tid; idx < 484; idx += 256) {
                int r = idx / 22, cl = idx - r*22;
                float v0 = s_in[0][r][cl], v1 = s_in[1][r][cl];
                float sc = 1.f / fmaxf(sqrtf(v0*v0 + v1*v1), 1e-12f);
                s_in[0][r][cl] = v0*sc; s_in[1][r][cl] = v1*sc;
            }
            __syncthreads();
        }
        #pragma unroll
        for (int ch = 0; ch < 2; ++ch)
            #pragma unroll
            for (int dy = 0; dy < 7; ++dy) {
                float r[12];
                const float* rp = &s_in[ch][ry + dy][sx*4];
                #pragma unroll
                for (int i = 0; i < 12; ++i) r[i] = rp[i];
                #pragma unroll
                for (int dx = 0; dx < 7; ++dx) {
                    const float* wv = &s_w[ch][dy*7 + dx][ocg*4];
                    float w0 = wv[0], w1 = wv[1], w2 = wv[2], w3 = wv[3];
                    #pragma unroll
                    for (int p = 0; p < 4; ++p) {
                        float iv = r[dx + p];
                        acc[0][p] = fmaf(w0, iv, acc[0][p]);
                        acc[1][p] = fmaf(w1, iv, acc[1][p]);
                        acc[2][p] = fmaf(w2, iv, acc[2][p]);
                        acc[3][p] = fmaf(w3, iv, acc[3][p]);
                    }
                }
            }
    }
    const int py = row0 + ry, px0 = col0 + sx*4;
    const float om = omega[0];
    const int ocbase = ocb*16 + ocg*4;
    float esum = 0.f;
    #pragma unroll
    for (int pr = 0; pr < 2; ++pr) {
        const int oc0 = ocbase + pr*2;
        const int g = oc0 >> 1;
        const float mu = stats[(b*64+g)*2], rs = stats[(b*64+g)*2+1];
        const float w0s = gnw[oc0]*rs,   b0s = gnb[oc0]   - mu*rs*gnw[oc0];
        const float w1s = gnw[oc0+1]*rs, b1s = gnb[oc0+1] - mu*rs*gnw[oc0+1];
        const float cb0 = cb[oc0], cb1 = cb[oc0+1];
        const size_t off = in_base + (size_t)oc0*HWSZ + py*IMG_W + px0;
        const float* c0p = craw + off; const float* c1p = c0p + HWSZ;
        const float* x0p = xin  + off; const float* x1p = x0p + HWSZ;
        float* o0p = xout + off; float* o1p = o0p + HWSZ;
        #pragma unroll
        for (int p = 0; p < 4; ++p) {
            float x0 = x0p[p], x1 = x1p[p];
            if (FIRST) {
                float sc = 1.f / fmaxf(sqrtf(x0*x0 + x1*x1), 1e-12f);
                x0 *= sc; x1 *= sc;
            }
            float y0 = acc[pr*2][p]   + cb0 + fmaf(c0p[p], w0s, b0s);
            float y1 = acc[pr*2+1][p] + cb1 + fmaf(c1p[p], w1s, b1s);
            float inner = x0*y0 + x1*y1;
            esum += inner;
            float xn0 = x0 - om*x1 + (y0 - inner*x0);
            float xn1 = x1 + om*x0 + (y1 - inner*x1);
            float sc2 = 1.f / fmaxf(sqrtf(xn0*xn0 + xn1*xn1), 1e-12f);
            o0p[p] = xn0*sc2; o1p[p] = xn1*sc2;
        }
    }
    s_red[tid] = esum;
    __syncthreads();
    for (int s = 128; s > 0; s >>= 1) {
        if (tid < s) s_red[tid] += s_red[tid + s];
        __syncthreads();
    }
    if (tid == 0) atomicAdd(es + b, -s_red[0]);
}

// ---------------------------------------------------------------------------
extern "C" void kernel_launch(void* const* d_in, const int* in_sizes, int n_in,
                              void* d_out, int out_size, void* d_ws, size_t ws_size,
                              hipStream_t stream)
{
    const float* x   = (const float*)d_in[0];
    const float* c   = (const float*)d_in[1];
    const float* cw  = (const float*)d_in[2];
    const float* cb  = (const float*)d_in[3];
    const float* gnw = (const float*)d_in[4];
    const float* gnb = (const float*)d_in[5];
    const float* om  = (const float*)d_in[6];
    float* out = (float*)d_out;

    float* stats = (float*)d_ws;
    hipMemsetAsync(out + ES_OFF, 0, 40 * sizeof(float), stream);
    gn_stats_kernel<<<512, 256, 0, stream>>>(c, stats);

    const size_t OFF_WQ  = 4096;
    const size_t OFF_CGN = OFF_WQ  + 802816;     //   806,912
    const size_t OFF_XQA = OFF_CGN + 18874368;   // 19,681,280
    const size_t OFF_XQB = OFF_XQA + XQ_BYTES;   // 30,334,976
    const size_t WS_NEED = OFF_XQB + XQ_BYTES;   // 40,988,672

    if (ws_size >= WS_NEED) {
        u32* wq   = (u32*)((char*)d_ws + OFF_WQ);
        u32* cgnp = (u32*)((char*)d_ws + OFF_CGN);
        u8*  xqA  = (u8*) ((char*)d_ws + OFF_XQA);
        u8*  xqB  = (u8*) ((char*)d_ws + OFF_XQB);

        hipMemsetAsync(xqA, 0, XQ_BYTES, stream);
        hipMemsetAsync(xqB, 0, XQ_BYTES, stream);
        wprep_kernel<<<(200704 + 255)/256, 256, 0, stream>>>(cw, wq);
        cprep_kernel<<<dim3(9, 512), 256, 0, stream>>>(c, stats, gnw, gnb, cb, cgnp);
        xprep_kernel<<<dim3(144, 8), 256, 0, stream>>>(x, xqA);

        dim3 grid(64, 8);
        u8* xin  = xqA;
        u8* xalt = xqB;
        for (int t = 0; t < NT; ++t) {
            float* xo  = out + (size_t)t * XS_ELEMS;
            float* esl = out + ES_OFF + (t + 1) * 8;
            int wb = (t < NT-1) ? 1 : 0;
            convk8<<<grid, 384, 0, stream>>>((const u8*)xin, (const u8*)wq, cgnp,
                                             om, xo, xalt, esl, wb);
            u8* tmp = xin; xin = xalt; xalt = tmp;
        }
    } else {
        dim3 grid(36, 8, 8);
        const float* xin = x;
        for (int t = 0; t < NT; ++t) {
            float* xo  = out + (size_t)t * XS_ELEMS;
            float* esl = out + ES_OFF + (t + 1) * 8;
            if (t == 0)
                conv_kur_kernel<true ><<<grid, 256, 0, stream>>>(xin, c, cw, cb, gnw, gnb, om, stats, xo, esl);
            else
                conv_kur_kernel<false><<<grid, 256, 0, stream>>>(xin, c, cw, cb, gnw, gnb, om, stats, xo, esl);
            xin = xo;
        }
    }
}